// Round 3
// baseline (1046.504 us; speedup 1.0000x reference)
//
#include <hip/hip_runtime.h>

#define NBUS 118
#define BATCH 4096
#define NN (BATCH * NBUS)          // 483328 nodes
#define END_E (4 * NN)             // 1933312 no-diag edges
#define EF_E (END_E + NN)          // 2416640 full edges
#define NLAYERS 10

#define NFB 944                    // fine dst buckets, span 512: 944*512 == NN
#define NFBP 1024                  // padded (pow2) for scan
#define FB_SHIFT 9
#define FB_MASK 511
#define TILE 4096                  // edges per binA block
#define ND_TILES (END_E / TILE)    // 472 (exact)
#define F_TILES  (EF_E / TILE)     // 590 (exact)
#define CAP_ND 2432                // mean 2048, +8.5 sigma
#define CAP_F  2944                // mean 2560, +7.6 sigma

#define W_ND 8                     // ELL width (even; on overflow slot W-1 = descriptor)
#define W_F 10
#define TAILCAP 1048576

#define NERR 64                    // spread error-atomic slots (stride 16 floats = 64B)

typedef int v4i __attribute__((ext_vector_type(4)));
__device__ __forceinline__ v4i ntl4(const v4i* p) { return __builtin_nontemporal_load(p); }
__device__ __forceinline__ float wf(int bits) { return __int_as_float(bits); }

// ---------- K1: p, denomInv, cursors, err partials ----------
__global__ void init_kernel(const float* __restrict__ x,
                            const float* __restrict__ ybus,
                            float* __restrict__ p,
                            float* __restrict__ denomInv,
                            int* __restrict__ cursor_nd,
                            int* __restrict__ cursor_f,
                            int* __restrict__ tailCur,
                            float* __restrict__ errPartial) {
    int tid = blockIdx.x * blockDim.x + threadIdx.x;
    int stride = gridDim.x * blockDim.x;
    for (int i = tid; i < NN; i += stride) {
        float2 xi = ((const float2*)x)[i];
        p[i] = xi.x - xi.y;
        int b = i / NBUS;
        int j = i - b * NBUS;
        denomInv[i] = 1.0f / (ybus[b * (NBUS * NBUS) + j * (NBUS + 1)] * 100.0f);
    }
    for (int i = tid; i < (NLAYERS + 1) * NERR * 16; i += stride) errPartial[i] = 0.0f;
    if (tid < NFBP) {
        cursor_nd[tid] = tid * CAP_ND;
        cursor_f[tid]  = tid * CAP_F;
    }
    if (tid < 2) tailCur[tid] = 0;
}

// ---------- K2 (binA): tile -> LDS bin by FINE bucket -> chunked staging writes ----------
// staged entry: .x = src | (dstLocal9<<19), .y = bits(w*100)
__global__ __launch_bounds__(256) void binA_kernel(
        const int* __restrict__ src_nd, const int* __restrict__ dst_nd,
        const float* __restrict__ ea_nd,
        const int* __restrict__ src_f, const int* __restrict__ dst_f,
        const float* __restrict__ ea_f,
        int* __restrict__ cursor_nd, int* __restrict__ cursor_f,
        uint2* __restrict__ stg_nd, uint2* __restrict__ stg_f) {
    __shared__ uint2 buf[TILE];              // 32 KB
    __shared__ unsigned short sb[TILE];      // 8 KB
    __shared__ int hist[NFBP];               // 4 KB: counts, then write-cursor
    __shared__ int delta[NFBP];              // 4 KB
    __shared__ int tsum[256];                // 1 KB

    bool isF = blockIdx.x >= ND_TILES;
    int tile = isF ? (blockIdx.x - ND_TILES) : blockIdx.x;
    const int* src = isF ? src_f : src_nd;
    const int* dst = isF ? dst_f : dst_nd;
    const float* ea = isF ? ea_f : ea_nd;
    int* cursor = isF ? cursor_f : cursor_nd;
    uint2* stg = isF ? stg_f : stg_nd;
    int cap = isF ? CAP_F : CAP_ND;

    int tid = threadIdx.x;
    int base = tile * TILE;

    #pragma unroll
    for (int k = 0; k < NFBP / 256; ++k) hist[k * 256 + tid] = 0;
    __syncthreads();

    #pragma unroll
    for (int k = 0; k < TILE / 256; ++k) {
        int d = dst[base + k * 256 + tid];
        atomicAdd(&hist[d >> FB_SHIFT], 1);
    }
    __syncthreads();

    int c0 = hist[tid * 4 + 0], c1 = hist[tid * 4 + 1];
    int c2 = hist[tid * 4 + 2], c3 = hist[tid * 4 + 3];
    int s = c0 + c1 + c2 + c3;
    tsum[tid] = s;
    __syncthreads();
    for (int off = 1; off < 256; off <<= 1) {
        int t = (tid >= off) ? tsum[tid - off] : 0;
        __syncthreads();
        tsum[tid] += t;
        __syncthreads();
    }
    int basex = tsum[tid] - s;
    {
        int st[4];
        st[0] = basex; st[1] = basex + c0; st[2] = st[1] + c1; st[3] = st[2] + c2;
        int cc[4] = {c0, c1, c2, c3};
        #pragma unroll
        for (int k = 0; k < 4; ++k) {
            int bkt = tid * 4 + k;
            hist[bkt] = st[k];
            if (bkt < NFB && cc[k] > 0) {
                int gb = atomicAdd(&cursor[bkt], cc[k]);
                delta[bkt] = gb - st[k];
            }
        }
    }
    __syncthreads();

    #pragma unroll
    for (int k = 0; k < TILE / 256; ++k) {
        int e = base + k * 256 + tid;
        int d = dst[e];
        int bkt = d >> FB_SHIFT;
        int pos = atomicAdd(&hist[bkt], 1);
        unsigned dl = (unsigned)(d & FB_MASK);
        buf[pos] = make_uint2((unsigned)src[e] | (dl << 19),
                              (unsigned)__float_as_int(ea[e] * 100.0f));
        sb[pos] = (unsigned short)bkt;
    }
    __syncthreads();

    #pragma unroll
    for (int k = 0; k < TILE / 256; ++k) {
        int slot = k * 256 + tid;
        int bkt = sb[slot];
        int gpos = delta[bkt] + slot;
        if (gpos < (bkt + 1) * cap)  // freak-overflow guard
            stg[gpos] = buf[slot];
    }
}

// ---------- K3 (binB): degree-sorted ELL build in LDS + per-rank meta ----------
// Nodes within a 512-node fine bucket are counting-sorted by degree DESC.
// ELL columns are RANKS; meta[rank] = nodeLocal(9b) | planes(3b)<<9 | desc(1b)<<12.
// Only the planes a rank actually needs are written (and later loaded).
__global__ __launch_bounds__(512) void binB_kernel(
        const uint2* __restrict__ stg_nd, const uint2* __restrict__ stg_f,
        const int* __restrict__ cursor_nd, const int* __restrict__ cursor_f,
        int2* __restrict__ ellND, int2* __restrict__ ellF,
        int2* __restrict__ tailND, int2* __restrict__ tailF,
        int* __restrict__ tailCur /* [0]=nd [1]=f */,
        unsigned short* __restrict__ metaND, unsigned short* __restrict__ metaF) {
    __shared__ int2 slice[512 * W_F];  // 40960 B (nd uses first 512*W_ND)
    __shared__ int h[512];             // per-node degree
    __shared__ int rk[512];            // per-node entry cursor
    __shared__ int tb[512];            // per-node tail base (overflow rows only)
    __shared__ int rkOf[512];          // node -> rank
    __shared__ int nodeOf[512];        // rank -> node
    __shared__ int dcnt[32];
    __shared__ int dpref[32];
    __shared__ int doff[32];

    int g = blockIdx.x;
    bool isF = g >= NFB;
    int fb = isF ? (g - NFB) : g;

    const uint2* stg = isF ? stg_f : stg_nd;
    int cap = isF ? CAP_F : CAP_ND;
    int W = isF ? W_F : W_ND;
    int2* ell = isF ? ellF : ellND;
    int2* tail = isF ? tailF : tailND;
    int* tc = isF ? (tailCur + 1) : tailCur;
    unsigned short* meta = isF ? metaF : metaND;

    int cnt_all = (isF ? cursor_f[fb] : cursor_nd[fb]) - fb * cap;
    if (cnt_all > cap) cnt_all = cap;
    int stgBase = fb * cap;
    int tid = threadIdx.x;

    {
        int4* s4 = (int4*)slice;
        int n4 = (512 * W) / 2;
        for (int i = tid; i < n4; i += 512) s4[i] = make_int4(0, 0, 0, 0);
        h[tid] = 0;
        rk[tid] = 0;
        if (tid < 32) { dcnt[tid] = 0; doff[tid] = 0; }
    }
    __syncthreads();

    // phase 1: per-node degree histogram
    for (int i = tid; i < cnt_all; i += 512) {
        uint2 v = stg[stgBase + i];
        atomicAdd(&h[(v.x >> 19) & FB_MASK], 1);
    }
    __syncthreads();

    // phase 2a: counting sort by degree (descending)
    int c = h[tid];
    int dckey = 31 - (c < 31 ? c : 31);
    atomicAdd(&dcnt[dckey], 1);
    __syncthreads();
    if (tid == 0) {
        int acc = 0;
        for (int k = 0; k < 32; ++k) { dpref[k] = acc; acc += dcnt[k]; }
    }
    __syncthreads();
    int myrank = dpref[dckey] + atomicAdd(&doff[dckey], 1);
    rkOf[tid] = myrank;
    nodeOf[myrank] = tid;
    __syncthreads();

    // phase 2b: tail allocation + descriptor for overflow rows (c > W)
    if (c > W) {
        int len = c - (W - 1);
        int tbase = atomicAdd(tc, len);
        if (tbase + len > TAILCAP) { tbase = 0; len = 0; }  // freak guard
        tb[tid] = tbase;
        slice[(W - 1) * 512 + myrank] = make_int2(len, tbase);  // plain (len, tbase)
    }
    __syncthreads();

    // phase 3: scatter staged -> LDS slice (column = rank) / global tail
    for (int i = tid; i < cnt_all; i += 512) {
        uint2 v = stg[stgBase + i];
        int dl = (v.x >> 19) & FB_MASK;
        int cn = h[dl];
        int r = atomicAdd(&rk[dl], 1);
        int plain = (cn <= W) ? cn : (W - 1);
        int2 pr = make_int2((int)(v.x & 0x7FFFF), (int)v.y);
        if (r < plain) slice[r * 512 + rkOf[dl]] = pr;
        else {
            int pos = tb[dl] + r - plain;
            if (pos < TAILCAP) tail[pos] = pr;
        }
    }
    __syncthreads();

    // phase 4: per-rank meta + variable-width pair-plane write-out (coalesced: sorted)
    {
        int dl = nodeOf[tid];
        int cn = h[dl];
        int np = (cn > W) ? (W >> 1) : ((cn + 1) >> 1);
        int desc = (cn > W) ? 1 : 0;
        meta[fb * 512 + tid] = (unsigned short)(dl | (np << 9) | (desc << 12));
        int nodeStart = fb * 512;
        v4i* ell4 = (v4i*)ell;
        for (int pp = 0; pp < np; ++pp) {
            int2 a  = slice[(2 * pp) * 512 + tid];
            int2 b2 = slice[(2 * pp + 1) * 512 + tid];
            v4i val; val.x = a.x; val.y = a.y; val.z = b2.x; val.w = b2.y;
            __builtin_nontemporal_store(val, ell4 + (long)pp * NN + nodeStart + tid);
        }
    }
}

// ---------- K4: layer 0 (theta = 0): out0 = p*denomInv - slack ----------
__global__ void out0_kernel(const float* __restrict__ p,
                            const float* __restrict__ denomInv,
                            float* __restrict__ out) {
    int b = blockIdx.x;
    int j = threadIdx.x;
    int i = b * NBUS + j;
    __shared__ float z0;
    float z = 0.0f;
    if (j < NBUS) z = p[i] * denomInv[i];
    if (j == 0) z0 = z;
    __syncthreads();
    if (j < NBUS) out[i] = z - z0;
}

__device__ __forceinline__ float tail_sum(const int2* __restrict__ tail, int tbase, int len,
                                          const float* __restrict__ cur) {
    float s = 0.0f;
    int t = 0;
    for (; t + 2 <= len; t += 2) {
        int2 a = tail[tbase + t];
        int2 b = tail[tbase + t + 1];
        s += cur[a.x] * wf(a.y) + cur[b.x] * wf(b.y);
    }
    if (t < len) {
        int2 a = tail[tbase + t];
        s += cur[a.x] * wf(a.y);
    }
    return s;
}

// ---------- K5: fused layer over RANKS: F edges -> err partials; ND edges -> zRaw ----------
// Thread i = global rank. metaF/metaND give the node + plane count for each side
// (they address DIFFERENT nodes; err is order-free, zRaw is written scattered
// within the 2KB bucket window). All 256 lanes active (NN = 1888*256 exactly).
template <bool DO_OUT>
__global__ __launch_bounds__(256) void layer_kernel(
        const int2* __restrict__ ellND, const int2* __restrict__ tailND,
        const int2* __restrict__ ellF, const int2* __restrict__ tailF,
        const unsigned short* __restrict__ metaND,
        const unsigned short* __restrict__ metaF,
        const float* __restrict__ cur,
        const float* __restrict__ p,
        const float* __restrict__ denomInv,
        float* __restrict__ zOut,
        float* __restrict__ errPart /* NERR slots, stride 16 */) {
    int tid = threadIdx.x;
    int i = blockIdx.x * 256 + tid;
    int bucketBase = i & ~FB_MASK;
    __shared__ float ws[4];

    // ---- F side (error) ----
    unsigned mf = metaF[i];
    int node_f = bucketBase + (int)(mf & 511u);
    int npf = (mf >> 9) & 7;
    int descf = (mf >> 12) & 1;
    float sum_f = 0.0f;
    {
        const v4i* eF = (const v4i*)ellF;
        v4i rr[W_F / 2];
        #pragma unroll
        for (int pp = 0; pp < W_F / 2; ++pp)
            if (pp < npf) rr[pp] = ntl4(eF + (long)pp * NN + i);
        #pragma unroll
        for (int pp = 0; pp < W_F / 2; ++pp) {
            if (pp < npf) {
                if (pp + 1 == npf && descf) {
                    sum_f += cur[rr[pp].x] * wf(rr[pp].y);
                    sum_f += tail_sum(tailF, rr[pp].w, rr[pp].z, cur);
                } else {
                    sum_f += cur[rr[pp].x] * wf(rr[pp].y) + cur[rr[pp].z] * wf(rr[pp].w);
                }
            }
        }
    }
    float acc = fabsf(p[node_f] - sum_f);

    // ---- ND side (zRaw) ----
    if (DO_OUT) {
        unsigned mn = metaND[i];
        int node_n = bucketBase + (int)(mn & 511u);
        int npn = (mn >> 9) & 7;
        int descn = (mn >> 12) & 1;
        float sum_nd = 0.0f;
        const v4i* eN = (const v4i*)ellND;
        v4i qq[W_ND / 2];
        #pragma unroll
        for (int pp = 0; pp < W_ND / 2; ++pp)
            if (pp < npn) qq[pp] = ntl4(eN + (long)pp * NN + i);
        #pragma unroll
        for (int pp = 0; pp < W_ND / 2; ++pp) {
            if (pp < npn) {
                if (pp + 1 == npn && descn) {
                    sum_nd += cur[qq[pp].x] * wf(qq[pp].y);
                    sum_nd += tail_sum(tailND, qq[pp].w, qq[pp].z, cur);
                } else {
                    sum_nd += cur[qq[pp].x] * wf(qq[pp].y) + cur[qq[pp].z] * wf(qq[pp].w);
                }
            }
        }
        zOut[node_n] = (p[node_n] - sum_nd) * denomInv[node_n];
    }

    // ---- error reduce ----
    for (int off = 32; off > 0; off >>= 1) acc += __shfl_down(acc, off, 64);
    if ((tid & 63) == 0) ws[tid >> 6] = acc;
    __syncthreads();
    if (tid == 0)
        atomicAdd(&errPart[(blockIdx.x & (NERR - 1)) * 16], ws[0] + ws[1] + ws[2] + ws[3]);
}

// ---------- K5b: slack subtraction: out[i] = z[i] - z[batch ref] ----------
__global__ __launch_bounds__(256) void slack_kernel(const float* __restrict__ zt,
                                                    float* __restrict__ out) {
    int tid = threadIdx.x;
    int sub = tid >> 7;
    int j = tid & 127;
    int b = (blockIdx.x << 1) | sub;
    int i = b * NBUS + j;
    __shared__ float z0s[2];
    float z = 0.0f;
    if (j < NBUS) z = zt[i];
    if (j == 0) z0s[sub] = z;
    __syncthreads();
    if (j < NBUS) out[i] = z - z0s[sub];
}

// ---------- K6: reduce err partials -> errs[11] ----------
__global__ void err_reduce_kernel(const float* __restrict__ errPartial,
                                  float* __restrict__ errs) {
    int l = blockIdx.x;
    int t = threadIdx.x;  // 64
    float v = errPartial[l * (NERR * 16) + t * 16];
    for (int off = 32; off > 0; off >>= 1) v += __shfl_down(v, off, 64);
    if (t == 0) errs[l] = v;
}

extern "C" void kernel_launch(void* const* d_in, const int* in_sizes, int n_in,
                              void* d_out, int out_size, void* d_ws, size_t ws_size,
                              hipStream_t stream) {
    const float* x     = (const float*)d_in[0];
    const int*   ei_nd = (const int*)d_in[2];
    const float* ea_nd = (const float*)d_in[3];
    const int*   ei    = (const int*)d_in[4];
    const float* ea    = (const float*)d_in[5];
    const float* ybus  = (const float*)d_in[6];

    float* out_f = (float*)d_out;
    float* errs  = out_f + NN;

    // workspace carve (4-byte units; ELL planes must stay 16B-aligned for int4)
    float* wsf        = (float*)d_ws;
    float* p          = wsf;          wsf += NN;
    float* denomInv   = wsf;          wsf += NN;
    float* outA       = wsf;          wsf += NN;
    float* outB       = wsf;          wsf += NN;
    float* zTmp       = wsf;          wsf += NN;
    int*   cursor_nd  = (int*)wsf;    wsf += NFBP;
    int*   cursor_f   = (int*)wsf;    wsf += NFBP;
    int*   tailCur    = (int*)wsf;    wsf += 4;
    float* errPartial = wsf;          wsf += (NLAYERS + 1) * NERR * 16;  // 11264
    unsigned short* metaND = (unsigned short*)wsf;  wsf += NN / 2;
    unsigned short* metaF  = (unsigned short*)wsf;  wsf += NN / 2;
    int2*  ellND      = (int2*)wsf;   wsf += 2LL * W_ND * NN;
    int2*  ellF       = (int2*)wsf;   wsf += 2LL * W_F * NN;
    int2*  tailND     = (int2*)wsf;   wsf += 2LL * TAILCAP;
    int2*  tailF      = (int2*)wsf;   wsf += 2LL * TAILCAP;
    uint2* stg_nd     = (uint2*)wsf;  wsf += 2LL * NFB * CAP_ND;
    uint2* stg_f      = (uint2*)wsf;  wsf += 2LL * NFB * CAP_F;

    const int* src_nd = ei_nd;
    const int* dst_nd = ei_nd + END_E;
    const int* src_f  = ei;
    const int* dst_f  = ei + EF_E;

    // ---- build phase ----
    init_kernel<<<2048, 256, 0, stream>>>(x, ybus, p, denomInv,
                                          cursor_nd, cursor_f, tailCur, errPartial);
    binA_kernel<<<ND_TILES + F_TILES, 256, 0, stream>>>(
        src_nd, dst_nd, ea_nd, src_f, dst_f, ea,
        cursor_nd, cursor_f, stg_nd, stg_f);
    binB_kernel<<<2 * NFB, 512, 0, stream>>>(
        stg_nd, stg_f, cursor_nd, cursor_f,
        ellND, ellF, tailND, tailF, tailCur, metaND, metaF);

    // ---- iterate phase ----
    out0_kernel<<<BATCH, 128, 0, stream>>>(p, denomInv, outA);
    const float* cur = outA;
    for (int k = 1; k <= NLAYERS; ++k) {
        layer_kernel<true><<<NN / 256, 256, 0, stream>>>(
            ellND, tailND, ellF, tailF, metaND, metaF, cur, p, denomInv, zTmp,
            errPartial + (long)(k - 1) * NERR * 16);
        float* nxt = (k == NLAYERS) ? out_f : ((k & 1) ? outB : outA);
        slack_kernel<<<BATCH / 2, 256, 0, stream>>>(zTmp, nxt);
        cur = nxt;
    }
    layer_kernel<false><<<NN / 256, 256, 0, stream>>>(
        ellND, tailND, ellF, tailF, metaND, metaF, cur, p, denomInv, nullptr,
        errPartial + (long)NLAYERS * NERR * 16);
    err_reduce_kernel<<<NLAYERS + 1, 64, 0, stream>>>(errPartial, errs);
}

// Round 4
// 884.393 us; speedup vs baseline: 1.1833x; 1.1833x over previous
//
#include <hip/hip_runtime.h>

#define NBUS 118
#define BATCH 4096
#define NN (BATCH * NBUS)          // 483328 nodes
#define END_E (4 * NN)             // 1933312 no-diag edges
#define EF_E (END_E + NN)          // 2416640 full edges
#define NLAYERS 10

#define SPAN 472                   // fine dst bucket span = 4*NBUS (batch-aligned!)
#define NFB 1024                   // 1024*472 == NN exactly
#define TILE 4096                  // edges per binA block
#define ND_TILES (END_E / TILE)    // 472 (exact)
#define F_TILES  (EF_E / TILE)     // 590 (exact)
#define CAP_ND 2304                // mean 1888, +9.5 sigma
#define CAP_F  2816                // mean 2360, +9.4 sigma

#define W_ND 8                     // ELL slots (slot W-1 = tail descriptor on overflow)
#define W_F 10
#define TAILCAP 1048576

#define NERR 64                    // spread error-atomic slots (stride 16 floats = 64B)

typedef int v4i __attribute__((ext_vector_type(4)));
__device__ __forceinline__ v4i ntl4(const v4i* p) { return __builtin_nontemporal_load(p); }
__device__ __forceinline__ float wf(int bits) { return __int_as_float(bits); }

// ---------- K1: p, denomInv, cursors, err partials ----------
__global__ void init_kernel(const float* __restrict__ x,
                            const float* __restrict__ ybus,
                            float* __restrict__ p,
                            float* __restrict__ denomInv,
                            int* __restrict__ cursor_nd,
                            int* __restrict__ cursor_f,
                            int* __restrict__ tailCur,
                            float* __restrict__ errPartial) {
    int tid = blockIdx.x * blockDim.x + threadIdx.x;
    int stride = gridDim.x * blockDim.x;
    for (int i = tid; i < NN; i += stride) {
        float2 xi = ((const float2*)x)[i];
        p[i] = xi.x - xi.y;
        int b = i / NBUS;
        int j = i - b * NBUS;
        denomInv[i] = 1.0f / (ybus[b * (NBUS * NBUS) + j * (NBUS + 1)] * 100.0f);
    }
    for (int i = tid; i < (NLAYERS + 1) * NERR * 16; i += stride) errPartial[i] = 0.0f;
    if (tid < NFB) {
        cursor_nd[tid] = tid * CAP_ND;
        cursor_f[tid]  = tid * CAP_F;
    }
    if (tid < 2) tailCur[tid] = 0;
}

// ---------- K2 (binA): tile -> LDS bin by fine bucket (span 472) -> staging ----------
// staged entry: .x = src | (dstLocal<<19)  (dl < 472, 9 bits), .y = bits(w*100)
__global__ __launch_bounds__(256) void binA_kernel(
        const int* __restrict__ src_nd, const int* __restrict__ dst_nd,
        const float* __restrict__ ea_nd,
        const int* __restrict__ src_f, const int* __restrict__ dst_f,
        const float* __restrict__ ea_f,
        int* __restrict__ cursor_nd, int* __restrict__ cursor_f,
        uint2* __restrict__ stg_nd, uint2* __restrict__ stg_f) {
    __shared__ uint2 buf[TILE];              // 32 KB
    __shared__ unsigned short sb[TILE];      // 8 KB
    __shared__ int hist[NFB];                // 4 KB: counts, then write-cursor
    __shared__ int delta[NFB];               // 4 KB
    __shared__ int tsum[256];                // 1 KB

    bool isF = blockIdx.x >= ND_TILES;
    int tile = isF ? (blockIdx.x - ND_TILES) : blockIdx.x;
    const int* src = isF ? src_f : src_nd;
    const int* dst = isF ? dst_f : dst_nd;
    const float* ea = isF ? ea_f : ea_nd;
    int* cursor = isF ? cursor_f : cursor_nd;
    uint2* stg = isF ? stg_f : stg_nd;
    int cap = isF ? CAP_F : CAP_ND;

    int tid = threadIdx.x;
    int base = tile * TILE;

    #pragma unroll
    for (int k = 0; k < NFB / 256; ++k) hist[k * 256 + tid] = 0;
    __syncthreads();

    #pragma unroll
    for (int k = 0; k < TILE / 256; ++k) {
        unsigned d = (unsigned)dst[base + k * 256 + tid];
        atomicAdd(&hist[d / SPAN], 1);
    }
    __syncthreads();

    int c0 = hist[tid * 4 + 0], c1 = hist[tid * 4 + 1];
    int c2 = hist[tid * 4 + 2], c3 = hist[tid * 4 + 3];
    int s = c0 + c1 + c2 + c3;
    tsum[tid] = s;
    __syncthreads();
    for (int off = 1; off < 256; off <<= 1) {
        int t = (tid >= off) ? tsum[tid - off] : 0;
        __syncthreads();
        tsum[tid] += t;
        __syncthreads();
    }
    int basex = tsum[tid] - s;
    {
        int st[4];
        st[0] = basex; st[1] = basex + c0; st[2] = st[1] + c1; st[3] = st[2] + c2;
        int cc[4] = {c0, c1, c2, c3};
        #pragma unroll
        for (int k = 0; k < 4; ++k) {
            int bkt = tid * 4 + k;
            hist[bkt] = st[k];
            if (cc[k] > 0) {
                int gb = atomicAdd(&cursor[bkt], cc[k]);
                delta[bkt] = gb - st[k];
            }
        }
    }
    __syncthreads();

    #pragma unroll
    for (int k = 0; k < TILE / 256; ++k) {
        int e = base + k * 256 + tid;
        unsigned d = (unsigned)dst[e];
        unsigned bkt = d / SPAN;
        int pos = atomicAdd(&hist[bkt], 1);
        unsigned dl = d - bkt * SPAN;
        buf[pos] = make_uint2((unsigned)src[e] | (dl << 19),
                              (unsigned)__float_as_int(ea[e] * 100.0f));
        sb[pos] = (unsigned short)bkt;
    }
    __syncthreads();

    #pragma unroll
    for (int k = 0; k < TILE / 256; ++k) {
        int slot = k * 256 + tid;
        int bkt = sb[slot];
        int gpos = delta[bkt] + slot;
        if (gpos < (bkt + 1) * cap)  // freak-overflow guard
            stg[gpos] = buf[slot];
    }
}

// ---------- K3 (binB): degree-sorted variable-width ELL + permuted scalars ----------
// Ranks within a 472-node bucket are degree-sorted DESC. ELL columns = global
// rank gi = fb*472 + rank. meta[gi] = nodeLocal(9b) | E(3b)<<9 | desc(1b)<<12,
// where E = extra pair-planes beyond plane 0. Only planes 0..E are written.
// Also emits p_f / p_nd / di_nd permuted by rank so layer scalar reads coalesce.
__global__ __launch_bounds__(512) void binB_kernel(
        const uint2* __restrict__ stg_nd, const uint2* __restrict__ stg_f,
        const int* __restrict__ cursor_nd, const int* __restrict__ cursor_f,
        int2* __restrict__ ellND, int2* __restrict__ ellF,
        int2* __restrict__ tailND, int2* __restrict__ tailF,
        int* __restrict__ tailCur /* [0]=nd [1]=f */,
        unsigned short* __restrict__ metaND, unsigned short* __restrict__ metaF,
        const float* __restrict__ p, const float* __restrict__ denomInv,
        float* __restrict__ p_nd, float* __restrict__ di_nd,
        float* __restrict__ p_f) {
    __shared__ int2 slice[512 * W_F];  // 40960 B (nd uses first 512*W_ND)
    __shared__ int h[512];             // per-node degree
    __shared__ int rk[512];            // per-node entry cursor
    __shared__ int tb[512];            // per-node tail base (overflow rows only)
    __shared__ int rkOf[512];          // node -> rank
    __shared__ int nodeOf[512];        // rank -> node
    __shared__ int dcnt[32];
    __shared__ int dpref[32];
    __shared__ int doff[32];

    int g = blockIdx.x;
    bool isF = g >= NFB;
    int fb = isF ? (g - NFB) : g;

    const uint2* stg = isF ? stg_f : stg_nd;
    int cap = isF ? CAP_F : CAP_ND;
    int W = isF ? W_F : W_ND;
    int2* ell = isF ? ellF : ellND;
    int2* tail = isF ? tailF : tailND;
    int* tc = isF ? (tailCur + 1) : tailCur;
    unsigned short* meta = isF ? metaF : metaND;

    int cnt_all = (isF ? cursor_f[fb] : cursor_nd[fb]) - fb * cap;
    if (cnt_all > cap) cnt_all = cap;
    int stgBase = fb * cap;
    int tid = threadIdx.x;

    {
        int4* s4 = (int4*)slice;
        int n4 = (512 * W) / 2;
        for (int i = tid; i < n4; i += 512) s4[i] = make_int4(0, 0, 0, 0);
        h[tid] = 0;
        rk[tid] = 0;
        if (tid < 32) { dcnt[tid] = 0; doff[tid] = 0; }
    }
    __syncthreads();

    // phase 1: per-node degree histogram (dl < 472 always)
    for (int i = tid; i < cnt_all; i += 512) {
        uint2 v = stg[stgBase + i];
        atomicAdd(&h[(v.x >> 19) & 511], 1);
    }
    __syncthreads();

    // phase 2a: counting sort by degree DESC (real nodes 0..471 only)
    int c = 0;
    int dckey = 31;
    if (tid < SPAN) {
        c = h[tid];
        dckey = 31 - (c < 31 ? c : 31);
        atomicAdd(&dcnt[dckey], 1);
    }
    __syncthreads();
    if (tid == 0) {
        int acc = 0;
        for (int k = 0; k < 32; ++k) { dpref[k] = acc; acc += dcnt[k]; }
    }
    __syncthreads();
    int myrank = -1;
    if (tid < SPAN) {
        myrank = dpref[dckey] + atomicAdd(&doff[dckey], 1);
        rkOf[tid] = myrank;
        nodeOf[myrank] = tid;
    }
    __syncthreads();

    // phase 2b: tail allocation; desc slot (W-1) stores plain (len, tbase)
    if (tid < SPAN && c > W) {
        int len = c - (W - 1);
        int tbase = atomicAdd(tc, len);
        if (tbase + len > TAILCAP) { tbase = 0; len = 0; }  // freak guard
        tb[tid] = tbase;
        slice[(W - 1) * 512 + myrank] = make_int2(len, tbase);
    }
    __syncthreads();

    // phase 3: scatter staged -> LDS slice (column = rank) / global tail
    for (int i = tid; i < cnt_all; i += 512) {
        uint2 v = stg[stgBase + i];
        int dl = (v.x >> 19) & 511;
        int cn = h[dl];
        int r = atomicAdd(&rk[dl], 1);
        int plain = (cn <= W) ? cn : (W - 1);
        int2 pr = make_int2((int)(v.x & 0x7FFFF), (int)v.y);
        if (r < plain) slice[r * 512 + rkOf[dl]] = pr;
        else {
            int pos = tb[dl] + r - plain;
            if (pos < TAILCAP) tail[pos] = pr;
        }
    }
    __syncthreads();

    // phase 4: per-rank meta + permuted scalars + planes 0..E write-out
    if (tid < SPAN) {
        int node = nodeOf[tid];
        int cn = h[node];
        int desc = (cn > W) ? 1 : 0;
        int E = desc ? (W / 2 - 1) : (cn <= 2 ? 0 : (cn + 1) / 2 - 1);
        long gi = (long)fb * SPAN + tid;
        meta[gi] = (unsigned short)(node | (E << 9) | (desc << 12));
        int gnode = fb * SPAN + node;
        if (isF) {
            p_f[gi] = p[gnode];
        } else {
            p_nd[gi] = p[gnode];
            di_nd[gi] = denomInv[gnode];
        }
        v4i* ell4 = (v4i*)ell;
        for (int pp = 0; pp <= E; ++pp) {
            int2 a  = slice[(2 * pp) * 512 + tid];
            int2 b2 = slice[(2 * pp + 1) * 512 + tid];
            v4i val; val.x = a.x; val.y = a.y; val.z = b2.x; val.w = b2.y;
            __builtin_nontemporal_store(val, ell4 + (long)pp * NN + gi);
        }
    }
}

// ---------- K4: layer 0 (theta = 0): out0 = p*denomInv - slack ----------
__global__ void out0_kernel(const float* __restrict__ p,
                            const float* __restrict__ denomInv,
                            float* __restrict__ out) {
    int b = blockIdx.x;
    int j = threadIdx.x;
    int i = b * NBUS + j;
    __shared__ float z0;
    float z = 0.0f;
    if (j < NBUS) z = p[i] * denomInv[i];
    if (j == 0) z0 = z;
    __syncthreads();
    if (j < NBUS) out[i] = z - z0;
}

__device__ __forceinline__ float tail_sum(const int2* __restrict__ tail, int tbase, int len,
                                          const float* __restrict__ cur) {
    float s = 0.0f;
    int t = 0;
    for (; t + 2 <= len; t += 2) {
        int2 a = tail[tbase + t];
        int2 b = tail[tbase + t + 1];
        s += cur[a.x] * wf(a.y) + cur[b.x] * wf(b.y);
    }
    if (t < len) {
        int2 a = tail[tbase + t];
        s += cur[a.x] * wf(a.y);
    }
    return s;
}

// ---------- K5: fused layer over sorted ranks; slack fused via LDS zbuf ----------
// Block = one 472-node bucket = exactly 4 batches. Thread tid<472 = rank gi.
// All scalar reads (meta, p_f, p_nd, di_nd) coalesced; out write coalesced.
template <bool DO_OUT>
__global__ __launch_bounds__(512) void layer_kernel(
        const v4i* __restrict__ ellND4, const int2* __restrict__ tailND,
        const v4i* __restrict__ ellF4, const int2* __restrict__ tailF,
        const unsigned short* __restrict__ metaND,
        const unsigned short* __restrict__ metaF,
        const float* __restrict__ p_nd, const float* __restrict__ di_nd,
        const float* __restrict__ p_f,
        const float* __restrict__ cur,
        float* __restrict__ out,
        float* __restrict__ errPart /* NERR slots, stride 16 */) {
    int tid = threadIdx.x;
    int fb = blockIdx.x;
    long gi = (long)fb * SPAN + tid;
    int base = fb * SPAN;
    __shared__ float zbuf[SPAN];
    __shared__ float ws[8];
    bool act = tid < SPAN;

    float acc = 0.0f;
    if (act) {
        // ---- F side (error) ----
        unsigned mf = metaF[gi];
        int Ef = (mf >> 9) & 7;
        int descf = (mf >> 12) & 1;
        v4i r0 = ntl4(ellF4 + gi);
        float sum_f = cur[r0.x] * wf(r0.y) + cur[r0.z] * wf(r0.w);
        for (int pp = 1; pp <= Ef; ++pp) {
            v4i r = ntl4(ellF4 + (long)pp * NN + gi);
            sum_f += cur[r.x] * wf(r.y);
            if (pp == Ef && descf) sum_f += tail_sum(tailF, r.w, r.z, cur);
            else                   sum_f += cur[r.z] * wf(r.w);
        }
        acc = fabsf(p_f[gi] - sum_f);

        // ---- ND side (z) ----
        if (DO_OUT) {
            unsigned mn = metaND[gi];
            int node = mn & 511;
            int En = (mn >> 9) & 7;
            int descn = (mn >> 12) & 1;
            v4i q0 = ntl4(ellND4 + gi);
            float sum_nd = cur[q0.x] * wf(q0.y) + cur[q0.z] * wf(q0.w);
            for (int pp = 1; pp <= En; ++pp) {
                v4i q = ntl4(ellND4 + (long)pp * NN + gi);
                sum_nd += cur[q.x] * wf(q.y);
                if (pp == En && descn) sum_nd += tail_sum(tailND, q.w, q.z, cur);
                else                   sum_nd += cur[q.z] * wf(q.w);
            }
            zbuf[node] = (p_nd[gi] - sum_nd) * di_nd[gi];
        }
    }
    if (DO_OUT) {
        __syncthreads();
        if (act) {
            int bofs = (tid / NBUS) * NBUS;   // 4 batches per bucket, exact
            out[base + tid] = zbuf[tid] - zbuf[bofs];
        }
    }
    // ---- error reduce ----
    for (int off = 32; off > 0; off >>= 1) acc += __shfl_down(acc, off, 64);
    if ((tid & 63) == 0) ws[tid >> 6] = acc;
    __syncthreads();
    if (tid == 0) {
        float t = 0.0f;
        #pragma unroll
        for (int w = 0; w < 8; ++w) t += ws[w];
        atomicAdd(&errPart[(fb & (NERR - 1)) * 16], t);
    }
}

// ---------- K6: reduce err partials -> errs[11] ----------
__global__ void err_reduce_kernel(const float* __restrict__ errPartial,
                                  float* __restrict__ errs) {
    int l = blockIdx.x;
    int t = threadIdx.x;  // 64
    float v = errPartial[l * (NERR * 16) + t * 16];
    for (int off = 32; off > 0; off >>= 1) v += __shfl_down(v, off, 64);
    if (t == 0) errs[l] = v;
}

extern "C" void kernel_launch(void* const* d_in, const int* in_sizes, int n_in,
                              void* d_out, int out_size, void* d_ws, size_t ws_size,
                              hipStream_t stream) {
    const float* x     = (const float*)d_in[0];
    const int*   ei_nd = (const int*)d_in[2];
    const float* ea_nd = (const float*)d_in[3];
    const int*   ei    = (const int*)d_in[4];
    const float* ea    = (const float*)d_in[5];
    const float* ybus  = (const float*)d_in[6];

    float* out_f = (float*)d_out;
    float* errs  = out_f + NN;

    // workspace carve (4-byte units; ELL planes must stay 16B-aligned for int4)
    float* wsf        = (float*)d_ws;
    float* p          = wsf;          wsf += NN;
    float* denomInv   = wsf;          wsf += NN;
    float* outA       = wsf;          wsf += NN;
    float* outB       = wsf;          wsf += NN;
    int*   cursor_nd  = (int*)wsf;    wsf += NFB;
    int*   cursor_f   = (int*)wsf;    wsf += NFB;
    int*   tailCur    = (int*)wsf;    wsf += 4;
    float* errPartial = wsf;          wsf += (NLAYERS + 1) * NERR * 16;  // 11264
    unsigned short* metaND = (unsigned short*)wsf;  wsf += NN / 2;
    unsigned short* metaF  = (unsigned short*)wsf;  wsf += NN / 2;
    float* p_nd       = wsf;          wsf += NN;
    float* di_nd      = wsf;          wsf += NN;
    float* p_f        = wsf;          wsf += NN;
    int2*  ellND      = (int2*)wsf;   wsf += 2LL * W_ND * NN;
    int2*  ellF       = (int2*)wsf;   wsf += 2LL * W_F * NN;
    int2*  tailND     = (int2*)wsf;   wsf += 2LL * TAILCAP;
    int2*  tailF      = (int2*)wsf;   wsf += 2LL * TAILCAP;
    uint2* stg_nd     = (uint2*)wsf;  wsf += 2LL * NFB * CAP_ND;
    uint2* stg_f      = (uint2*)wsf;  wsf += 2LL * NFB * CAP_F;

    const int* src_nd = ei_nd;
    const int* dst_nd = ei_nd + END_E;
    const int* src_f  = ei;
    const int* dst_f  = ei + EF_E;

    // ---- build phase ----
    init_kernel<<<2048, 256, 0, stream>>>(x, ybus, p, denomInv,
                                          cursor_nd, cursor_f, tailCur, errPartial);
    binA_kernel<<<ND_TILES + F_TILES, 256, 0, stream>>>(
        src_nd, dst_nd, ea_nd, src_f, dst_f, ea,
        cursor_nd, cursor_f, stg_nd, stg_f);
    binB_kernel<<<2 * NFB, 512, 0, stream>>>(
        stg_nd, stg_f, cursor_nd, cursor_f,
        ellND, ellF, tailND, tailF, tailCur, metaND, metaF,
        p, denomInv, p_nd, di_nd, p_f);

    // ---- iterate phase ----
    out0_kernel<<<BATCH, 128, 0, stream>>>(p, denomInv, outA);
    const float* cur = outA;
    for (int k = 1; k <= NLAYERS; ++k) {
        float* nxt = (k == NLAYERS) ? out_f : ((k & 1) ? outB : outA);
        layer_kernel<true><<<NFB, 512, 0, stream>>>(
            (const v4i*)ellND, tailND, (const v4i*)ellF, tailF, metaND, metaF,
            p_nd, di_nd, p_f, cur, nxt,
            errPartial + (long)(k - 1) * NERR * 16);
        cur = nxt;
    }
    layer_kernel<false><<<NFB, 512, 0, stream>>>(
        (const v4i*)ellND, tailND, (const v4i*)ellF, tailF, metaND, metaF,
        p_nd, di_nd, p_f, cur, nullptr,
        errPartial + (long)NLAYERS * NERR * 16);
    err_reduce_kernel<<<NLAYERS + 1, 64, 0, stream>>>(errPartial, errs);
}